// Round 4
// baseline (392.644 us; speedup 1.0000x reference)
//
#include <hip/hip_runtime.h>

// ---------------------------------------------------------------------------
// DeformableTransformerEncoderLayer on MI355X (gfx950) — round 4
// Key change: A-resident GEMM. K is tiny (256/512), so the m97-style
// per-K-step staging+barrier loop is pure latency. Instead: stage the A-tile
// (64x256 or 32x512 = 32 KB, XOR-swizzled) in LDS ONCE per block (single
// barrier), then stream B (small, L2-hot weights) global->VGPR in a
// barrier-free K-loop. 8 waves/block, wave owns a J*16-col strip.
// sample_k: s_wo stored [4][128] to kill the 4-way LDS bank conflict.
// ---------------------------------------------------------------------------

typedef __bf16 bf16x8 __attribute__((ext_vector_type(8)));
typedef __bf16 bf16x4 __attribute__((ext_vector_type(4)));
typedef float floatx4 __attribute__((ext_vector_type(4)));

#define S_TOTAL 13294
#define M_ROWS  26588      // 2 * 13294
#define M_PAD   26624      // 416 * 64
#define DMODEL  256

// ---------------- fused weight conversion ----------------------------------
struct CvtArgs {
    const float *Woff, *Wattn, *Wval, *Wout, *W1, *W2, *boff, *battn;
};
__global__ __launch_bounds__(256) void cvt_all(CvtArgs a, __bf16* __restrict__ wdst,
                                               float* __restrict__ bc) {
    int i = blockIdx.x * 256 + threadIdx.x;
    if (i < 65536) {                                  // W_off^T -> comb rows 0..255
        wdst[i] = (__bf16)a.Woff[(i & 255) * 256 + (i >> 8)];
    } else if (i < 98304) {                           // W_attn^T -> comb rows 256..383
        int j = i - 65536;
        wdst[i] = (__bf16)a.Wattn[(j & 255) * 128 + (j >> 8)];
    } else if (i < 163840) {                          // W_val^T
        int j = i - 98304;
        wdst[i] = (__bf16)a.Wval[(j & 255) * 256 + (j >> 8)];
    } else if (i < 229376) {                          // W_out^T
        int j = i - 163840;
        wdst[i] = (__bf16)a.Wout[(j & 255) * 256 + (j >> 8)];
    } else if (i < 491520) {                          // W1^T (1024x256)
        int j = i - 229376;
        wdst[i] = (__bf16)a.W1[(j & 255) * 1024 + (j >> 8)];
    } else if (i < 753664) {                          // W2^T (256x1024)
        int j = i - 491520;
        wdst[i] = (__bf16)a.W2[(j & 1023) * 256 + (j >> 10)];
    } else if (i < 754048) {                          // bias concat
        int j = i - 753664;
        bc[j] = (j < 256) ? a.boff[j] : a.battn[j - 256];
    }
}

// ---------------- prep: qb = bf16(src+pos), srcb = bf16(src), zero-pad ------
__global__ __launch_bounds__(256) void prep_k(const float* __restrict__ src,
                                              const float* __restrict__ pos,
                                              __bf16* __restrict__ qb,
                                              __bf16* __restrict__ srcb) {
    int i4 = blockIdx.x * 256 + threadIdx.x;          // over M_PAD*256/4
    size_t e = (size_t)i4 * 4;
    if (e < (size_t)M_ROWS * DMODEL) {
        float4 s = *(const float4*)(src + e);
        float4 p = *(const float4*)(pos + e);
        bf16x4 q = {(__bf16)(s.x + p.x), (__bf16)(s.y + p.y),
                    (__bf16)(s.z + p.z), (__bf16)(s.w + p.w)};
        bf16x4 sb = {(__bf16)s.x, (__bf16)s.y, (__bf16)s.z, (__bf16)s.w};
        *(bf16x4*)(qb + e)   = q;
        *(bf16x4*)(srcb + e) = sb;
    } else {
        bf16x4 z = {(__bf16)0.f, (__bf16)0.f, (__bf16)0.f, (__bf16)0.f};
        *(bf16x4*)(qb + e)   = z;
        *(bf16x4*)(srcb + e) = z;
    }
}

// ---------------- A-resident bf16 MFMA GEMM --------------------------------
// A: (M x K) bf16 row-major, row stride lda. BT: (n x K...) bf16, row stride
// ldb. Block = 8 waves; block stages A-tile BM x KT in swizzled LDS once,
// then each wave computes a J*16-col strip with B streamed from global.
// C (+bias) (+relu) (+in-place f32 accum), f32 or bf16 out, row stride N.
template <int BM, int KT, int J, bool RELU, bool BF16OUT, bool ACCUM>
__global__ __launch_bounds__(512, 4) void gemm_ares(const __bf16* __restrict__ A,
                                                    int lda,
                                                    const __bf16* __restrict__ BT,
                                                    int ldb,
                                                    const float* __restrict__ bias,
                                                    float* __restrict__ Cf,
                                                    __bf16* __restrict__ Cb,
                                                    int N) {
    constexpr int GPR = KT / 8;                // 16B granules per A row
    __shared__ __align__(16) __bf16 As[BM * KT];            // 32 KB
    __shared__ __align__(16) float  patch[8][16 * 20];      // 10 KB epilogue

    const int tid  = threadIdx.x;
    const int row0 = blockIdx.y * BM;
    const int wave = tid >> 6, lane = tid & 63;
    const int l16  = lane & 15, quad = lane >> 4;

    // ---- stage A-tile (XOR-swizzled granules: g' = g ^ (row & 31)) --------
#pragma unroll
    for (int it = 0; it < BM * GPR / 512; it++) {
        int fg = it * 512 + tid;
        int m  = fg / GPR, g = fg % GPR;
        bf16x8 v = *(const bf16x8*)(A + (size_t)(row0 + m) * lda + g * 8);
        *(bf16x8*)(As + m * KT + (g ^ (m & 31)) * 8) = v;
    }
    __syncthreads();

    const int n0 = blockIdx.x * (8 * J * 16) + wave * (J * 16);
    floatx4 acc[BM / 16][J] = {};

#pragma unroll 4
    for (int ki = 0; ki < KT / 32; ki++) {
        bf16x8 af[BM / 16], bfr[J];
#pragma unroll
        for (int i = 0; i < BM / 16; i++) {
            int row = i * 16 + l16;
            int g   = ki * 4 + quad;
            af[i] = *(const bf16x8*)(As + row * KT + (g ^ (row & 31)) * 8);
        }
#pragma unroll
        for (int j = 0; j < J; j++) {
            int n = n0 + j * 16 + l16;
            bfr[j] = *(const bf16x8*)(BT + (size_t)n * ldb + ki * 32 + quad * 8);
        }
#pragma unroll
        for (int i = 0; i < BM / 16; i++)
#pragma unroll
            for (int j = 0; j < J; j++)
                acc[i][j] = __builtin_amdgcn_mfma_f32_16x16x32_bf16(
                    af[i], bfr[j], acc[i][j], 0, 0, 0);
    }

    // ---- epilogue: per-(i,j) 16x16 LDS transpose -> coalesced stores ------
    float bvj[J];
#pragma unroll
    for (int j = 0; j < J; j++) bvj[j] = bias ? bias[n0 + j * 16 + l16] : 0.f;

    float* pat = patch[wave];
    const int prow = lane >> 2, pc = lane & 3;
#pragma unroll
    for (int i = 0; i < BM / 16; i++)
#pragma unroll
        for (int j = 0; j < J; j++) {
#pragma unroll
            for (int r = 0; r < 4; r++) {
                float v = acc[i][j][r] + bvj[j];
                if (RELU) v = fmaxf(v, 0.f);
                pat[(quad * 4 + r) * 20 + l16] = v;
            }
            // same-wave LDS RAW: in-order per wave, lgkmcnt auto-inserted
            float4 v4 = *(float4*)&pat[prow * 20 + pc * 4];
            size_t gi = (size_t)(row0 + i * 16 + prow) * N + n0 + j * 16 + pc * 4;
            if (BF16OUT) {
                bf16x4 ob = {(__bf16)v4.x, (__bf16)v4.y, (__bf16)v4.z, (__bf16)v4.w};
                *(bf16x4*)(Cb + gi) = ob;
            } else if (ACCUM) {
                float4 c4 = *(const float4*)(Cf + gi);
                v4.x += c4.x; v4.y += c4.y; v4.z += c4.z; v4.w += c4.w;
                *(float4*)(Cf + gi) = v4;
            } else {
                *(float4*)(Cf + gi) = v4;
            }
        }
}

// ---------------- MSDeformAttn sampling ------------------------------------
// one block per padded row; offa: (M_PAD x 384) f32 = [off(256)|logits(128)]
__global__ __launch_bounds__(256) void sample_k(const float* __restrict__ offa,
                                                const __bf16* __restrict__ valb,
                                                const float* __restrict__ refp,
                                                __bf16* __restrict__ outb) {
    const int r   = blockIdx.x;
    const int tid = threadIdx.x;
    if (r >= M_ROWS) {
        outb[(size_t)r * 256 + tid] = (__bf16)0.f;
        return;
    }
    __shared__ float2 s_wo[4][128];    // [corner][point] {weight, byte-off bits}
    const int n = (r >= S_TOTAL) ? 1 : 0;

    if (tid < 128) {
        const int HLc[4] = {100, 50, 25, 13};
        const int STc[4] = {0, 10000, 12500, 13125};
        int lp = tid & 15, l = lp >> 2;
        float logit = offa[(size_t)r * 384 + 256 + tid];
        float mx = logit;
        mx = fmaxf(mx, __shfl_xor(mx, 1));
        mx = fmaxf(mx, __shfl_xor(mx, 2));
        mx = fmaxf(mx, __shfl_xor(mx, 4));
        mx = fmaxf(mx, __shfl_xor(mx, 8));
        float e = __expf(logit - mx);
        float s = e;
        s += __shfl_xor(s, 1); s += __shfl_xor(s, 2);
        s += __shfl_xor(s, 4); s += __shfl_xor(s, 8);
        float aw = e / s;

        float2 o2 = *(const float2*)(offa + (size_t)r * 384 + tid * 2);
        float rx = refp[((size_t)r * 4 + l) * 2];
        float ry = refp[((size_t)r * 4 + l) * 2 + 1];
        int   Wl = HLc[l];
        float x = rx * (float)Wl + o2.x - 0.5f;
        float y = ry * (float)Wl + o2.y - 0.5f;
        float xf = floorf(x), yf = floorf(y);
        float wx1 = x - xf, wy1 = y - yf;
        float wx0 = 1.f - wx1, wy0 = 1.f - wy1;
        int x0 = (int)xf, y0 = (int)yf;
        int base = n * S_TOTAL + STc[l];
#pragma unroll
        for (int c = 0; c < 4; c++) {
            int yy = y0 + (c >> 1), xx = x0 + (c & 1);
            bool valid = (yy >= 0) & (yy < Wl) & (xx >= 0) & (xx < Wl);
            int yc = min(max(yy, 0), Wl - 1);
            int xc = min(max(xx, 0), Wl - 1);
            float w = ((c >> 1) ? wy1 : wy0) * ((c & 1) ? wx1 : wx0);
            int off = (base + yc * Wl + xc) * 512;     // byte offset into valb
            s_wo[c][tid] = make_float2(valid ? w * aw : 0.f, __int_as_float(off));
        }
    }
    __syncthreads();

    // phase 2: tid = h(3) | pg(3) | cg(2): 8 ch/lane (bf16x8), 2 pts/lane,
    // reduce 8 point-groups via shfl_xor 4/8/16
    const int h  = tid >> 5;
    const int pg = (tid >> 2) & 7;
    const int cg = tid & 3;
    const char* vbase = (const char*)valb + h * 64 + cg * 16;
    float a[8] = {};
#pragma unroll
    for (int pp = 0; pp < 2; pp++) {
        int idx = h * 16 + pg * 2 + pp;
#pragma unroll
        for (int c = 0; c < 4; c++) {
            float2 wo = s_wo[c][idx];
            float  w  = wo.x;
            bf16x8 v  = *(const bf16x8*)(vbase + __float_as_int(wo.y));
#pragma unroll
            for (int k = 0; k < 8; k++) a[k] += w * (float)v[k];
        }
    }
#pragma unroll
    for (int k = 0; k < 8; k++) {
        a[k] += __shfl_xor(a[k], 4);
        a[k] += __shfl_xor(a[k], 8);
        a[k] += __shfl_xor(a[k], 16);
    }
    if (pg == 0) {
        bf16x8 res;
#pragma unroll
        for (int k = 0; k < 8; k++) res[k] = (__bf16)a[k];
        *(bf16x8*)(outb + (size_t)r * 256 + h * 32 + cg * 8) = res;
    }
}

// ---------------- LayerNorm kernels ----------------------------------------
__global__ __launch_bounds__(64) void ln1_k(const float* __restrict__ src,
                                            const float* __restrict__ src2,
                                            const float* __restrict__ g,
                                            const float* __restrict__ b,
                                            float* __restrict__ x,
                                            __bf16* __restrict__ xb) {
    const int r = blockIdx.x, lane = threadIdx.x;
    if (r >= M_ROWS) {
        bf16x4 z = {(__bf16)0.f, (__bf16)0.f, (__bf16)0.f, (__bf16)0.f};
        *(bf16x4*)(xb + (size_t)r * 256 + lane * 4) = z;
        return;
    }
    size_t base = (size_t)r * 256 + lane * 4;
    float4 a = *(const float4*)(src + base);
    float4 c = *(const float4*)(src2 + base);
    float v0 = a.x + c.x, v1 = a.y + c.y, v2 = a.z + c.z, v3 = a.w + c.w;
    float s  = v0 + v1 + v2 + v3;
    float sq = v0 * v0 + v1 * v1 + v2 * v2 + v3 * v3;
    for (int o = 32; o > 0; o >>= 1) {
        s  += __shfl_xor(s, o);
        sq += __shfl_xor(sq, o);
    }
    float mean = s * (1.f / 256.f);
    float var  = sq * (1.f / 256.f) - mean * mean;
    float rs   = rsqrtf(var + 1e-5f);
    float4 gg = *(const float4*)(g + lane * 4);
    float4 bb = *(const float4*)(b + lane * 4);
    float o0 = (v0 - mean) * rs * gg.x + bb.x;
    float o1 = (v1 - mean) * rs * gg.y + bb.y;
    float o2 = (v2 - mean) * rs * gg.z + bb.z;
    float o3 = (v3 - mean) * rs * gg.w + bb.w;
    *(float4*)(x + base) = make_float4(o0, o1, o2, o3);
    bf16x4 ob = {(__bf16)o0, (__bf16)o1, (__bf16)o2, (__bf16)o3};
    *(bf16x4*)(xb + base) = ob;
}

__global__ __launch_bounds__(64) void ln2_k(const float* __restrict__ t,
                                            const float* __restrict__ g,
                                            const float* __restrict__ b,
                                            float* __restrict__ out) {
    const int r = blockIdx.x, lane = threadIdx.x;
    size_t base = (size_t)r * 256 + lane * 4;
    float4 a = *(const float4*)(t + base);
    float v0 = a.x, v1 = a.y, v2 = a.z, v3 = a.w;
    float s  = v0 + v1 + v2 + v3;
    float sq = v0 * v0 + v1 * v1 + v2 * v2 + v3 * v3;
    for (int o = 32; o > 0; o >>= 1) {
        s  += __shfl_xor(s, o);
        sq += __shfl_xor(sq, o);
    }
    float mean = s * (1.f / 256.f);
    float var  = sq * (1.f / 256.f) - mean * mean;
    float rs   = rsqrtf(var + 1e-5f);
    float4 gg = *(const float4*)(g + lane * 4);
    float4 bb = *(const float4*)(b + lane * 4);
    float4 o4;
    o4.x = (v0 - mean) * rs * gg.x + bb.x;
    o4.y = (v1 - mean) * rs * gg.y + bb.y;
    o4.z = (v2 - mean) * rs * gg.z + bb.z;
    o4.w = (v3 - mean) * rs * gg.w + bb.w;
    *(float4*)(out + base) = o4;
}

// ---------------------------------------------------------------------------
extern "C" void kernel_launch(void* const* d_in, const int* in_sizes, int n_in,
                              void* d_out, int out_size, void* d_ws, size_t ws_size,
                              hipStream_t stream) {
    const float* src  = (const float*)d_in[0];
    const float* pos  = (const float*)d_in[1];
    const float* refp = (const float*)d_in[2];
    const float* W_off  = (const float*)d_in[5];
    const float* b_off  = (const float*)d_in[6];
    const float* W_attn = (const float*)d_in[7];
    const float* b_attn = (const float*)d_in[8];
    const float* W_val  = (const float*)d_in[9];
    const float* b_val  = (const float*)d_in[10];
    const float* W_out  = (const float*)d_in[11];
    const float* b_out  = (const float*)d_in[12];
    const float* W1     = (const float*)d_in[13];
    const float* b1     = (const float*)d_in[14];
    const float* W2     = (const float*)d_in[15];
    const float* b2     = (const float*)d_in[16];
    const float* g1     = (const float*)d_in[17];
    const float* beta1  = (const float*)d_in[18];
    const float* g2     = (const float*)d_in[19];
    const float* beta2  = (const float*)d_in[20];
    float* out = (float*)d_out;

    // ---- workspace layout (identical footprint to R3, peak ~97 MB) --------
    const size_t RB = (size_t)M_PAD * 256 * 2;   // 13,631,488
    const size_t RF = (size_t)M_PAD * 256 * 4;   // 27,262,976
    char* ws = (char*)d_ws;
    __bf16* qb   = (__bf16*)(ws);
    __bf16* srcb = (__bf16*)(ws + RB);
    float*  offa = (float*)(ws + 2 * RB);                              // M_PAD x 384
    __bf16* valb = (__bf16*)(ws + 2 * RB + (size_t)M_PAD * 384 * 4);
    __bf16* outb = qb;
    float*  src2 = (float*)(ws + RB);
    float*  x    = (float*)(ws + RB + RF);
    __bf16* xb   = qb;
    __bf16* hbh  = (__bf16*)(ws + 2 * RB + (size_t)M_PAD * 384 * 4);   // M_PAD x 512
    char*   regW = ws + 2 * RB + (size_t)M_PAD * 384 * 4 + (size_t)M_PAD * 512 * 2;

    __bf16* WTcomb = (__bf16*)regW;
    __bf16* WTval  = (__bf16*)(regW + 196608);
    __bf16* WTout  = (__bf16*)(regW + 327680);
    __bf16* WT1    = (__bf16*)(regW + 458752);
    __bf16* WT2    = (__bf16*)(regW + 983040);
    float*  bc     = (float*)(regW + 1507328);

    CvtArgs ca = {W_off, W_attn, W_val, W_out, W1, W2, b_off, b_attn};
    cvt_all<<<(754048 + 255) / 256, 256, 0, stream>>>(ca, WTcomb, bc);

    prep_k<<<M_PAD * 256 / 4 / 256, 256, 0, stream>>>(src, pos, qb, srcb);

    // fused off+attn projection (N=384: 8 waves x 48 cols) and value proj
    gemm_ares<64, 256, 3, false, false, false><<<dim3(1, 416), 512, 0, stream>>>(
        qb, 256, WTcomb, 256, bc, offa, nullptr, 384);
    gemm_ares<64, 256, 2, false, true, false><<<dim3(1, 416), 512, 0, stream>>>(
        srcb, 256, WTval, 256, b_val, nullptr, valb, 256);

    sample_k<<<M_PAD, 256, 0, stream>>>(offa, valb, refp, outb);

    gemm_ares<64, 256, 2, false, false, false><<<dim3(1, 416), 512, 0, stream>>>(
        outb, 256, WTout, 256, b_out, src2, nullptr, 256);
    ln1_k<<<M_PAD, 64, 0, stream>>>(src, src2, g1, beta1, x, xb);

    // FFN: halves h = 0,1; hbh region reused between halves
    for (int half = 0; half < 2; half++) {
        gemm_ares<64, 256, 2, true, true, false><<<dim3(2, 416), 512, 0, stream>>>(
            xb, 256, WT1 + (size_t)half * 512 * 256, 256, b1 + half * 512,
            nullptr, hbh, 512);
        gemm_ares<32, 512, 2, false, false, true><<<dim3(1, 832), 512, 0, stream>>>(
            hbh, 512, WT2 + half * 512, 1024, half == 0 ? b2 : nullptr,
            x, nullptr, 256);
    }
    ln2_k<<<M_ROWS, 64, 0, stream>>>(x, g2, beta2, out);
}

// Round 5
// 362.654 us; speedup vs baseline: 1.0827x; 1.0827x over previous
//
#include <hip/hip_runtime.h>

// ---------------------------------------------------------------------------
// DeformableTransformerEncoderLayer on MI355X (gfx950) — round 5
// 6 dispatches total (was 13). Fusion-first: the pipeline is bound by
// intermediate traffic + dispatch overhead, not MFMA.
//   cvt_k:    coalesced LDS-tiled weight transpose f32->bf16^T (+bias concat)
//   gemm_src: offa = bf16(src+pos) @ [W_off|W_attn] + bc   (A staged from f32)
//   gemm_src: valb = bf16(src) @ W_val + b_val             (bf16 out)
//   sample_k: outb = MSDeformAttn(offa, valb)
//   oln_k:    x,xb = LN(src + outb@W_out + b_out)          (GEMM+res+LN fused)
//   ffn_k:    out  = LN(x + relu(xb@W1+b1)@W2 + b2)        (whole FFN fused,
//             h-tile lives in LDS in two 512-col halves, never in HBM)
// ---------------------------------------------------------------------------

typedef __bf16 bf16x8 __attribute__((ext_vector_type(8)));
typedef __bf16 bf16x4 __attribute__((ext_vector_type(4)));
typedef float floatx4 __attribute__((ext_vector_type(4)));

#define S_TOTAL 13294
#define M_ROWS  26588
#define M_PAD   26624

#define MFMA16(a, b, c) __builtin_amdgcn_mfma_f32_16x16x32_bf16(a, b, c, 0, 0, 0)

// ---------------- weight transpose: 64x64 tiles via LDS --------------------
__global__ __launch_bounds__(256) void cvt_k(
    const float* __restrict__ Woff, const float* __restrict__ Wattn,
    const float* __restrict__ Wval, const float* __restrict__ Wout,
    const float* __restrict__ W1,   const float* __restrict__ W2,
    const float* __restrict__ boff, const float* __restrict__ battn,
    __bf16* __restrict__ wbase, float* __restrict__ bc) {
    int b = blockIdx.x;
    if (b >= 184) {                       // bias concat block
        for (int i = threadIdx.x; i < 384; i += 256)
            bc[i] = (i < 256) ? boff[i] : battn[i - 256];
        return;
    }
    const float* W; __bf16* D; int K, N, t;
    if (b < 16)       { W = Woff;  D = wbase;          K = 256;  N = 256;  t = b; }
    else if (b < 24)  { W = Wattn; D = wbase + 65536;  K = 256;  N = 128;  t = b - 16; }
    else if (b < 40)  { W = Wval;  D = wbase + 98304;  K = 256;  N = 256;  t = b - 24; }
    else if (b < 56)  { W = Wout;  D = wbase + 163840; K = 256;  N = 256;  t = b - 40; }
    else if (b < 120) { W = W1;    D = wbase + 229376; K = 256;  N = 1024; t = b - 56; }
    else              { W = W2;    D = wbase + 491520; K = 1024; N = 256;  t = b - 120; }
    int tk = K >> 6;
    int n0 = (t / tk) << 6, k0 = (t % tk) << 6;
    __shared__ float T[64][65];
    int tid = threadIdx.x;
    int rr = tid >> 4, cc = (tid & 15) << 2;
#pragma unroll
    for (int p = 0; p < 4; p++) {
        int r = p * 16 + rr;
        float4 v = *(const float4*)(W + (size_t)(k0 + r) * N + n0 + cc);
        T[r][cc] = v.x; T[r][cc + 1] = v.y; T[r][cc + 2] = v.z; T[r][cc + 3] = v.w;
    }
    __syncthreads();
#pragma unroll
    for (int p = 0; p < 4; p++) {
        int n = p * 16 + rr;              // dest row = source col
        bf16x4 o = {(__bf16)T[cc][n], (__bf16)T[cc + 1][n],
                    (__bf16)T[cc + 2][n], (__bf16)T[cc + 3][n]};
        *(bf16x4*)(D + (size_t)(n0 + n) * K + k0 + cc) = o;
    }
}

// ---------------- GEMM with A staged from f32 global -----------------------
// C[M_PAD x N] = bf16(Af (+Pf)) @ B + bias; BM=64, 8 waves, wave strip J*16.
template <int J, bool SUMPOS, bool BF16OUT>
__global__ __launch_bounds__(512, 4) void gemm_src(
    const float* __restrict__ Af, const float* __restrict__ Pf,
    const __bf16* __restrict__ BT, const float* __restrict__ bias,
    float* __restrict__ Cf, __bf16* __restrict__ Cb, int N) {
    constexpr int ASTR = 264;                       // +8: 2-way banks (free)
    __shared__ __align__(16) __bf16 As[64 * ASTR];
    __shared__ __align__(16) float patch[8][16 * 20];
    const int tid = threadIdx.x, wave = tid >> 6, lane = tid & 63;
    const int l16 = lane & 15, quad = lane >> 4;
    const int row0 = blockIdx.x * 64;
#pragma unroll
    for (int p = 0; p < 8; p++) {                   // stage+convert A
        int fe = (p * 512 + tid) * 4;
        int m = fe >> 8, k = fe & 255;
        int row = min(row0 + m, M_ROWS - 1);        // clamp: padded rows
        float4 s = *(const float4*)(Af + (size_t)row * 256 + k);
        if (SUMPOS) {
            float4 pp = *(const float4*)(Pf + (size_t)row * 256 + k);
            s.x += pp.x; s.y += pp.y; s.z += pp.z; s.w += pp.w;
        }
        bf16x4 v = {(__bf16)s.x, (__bf16)s.y, (__bf16)s.z, (__bf16)s.w};
        *(bf16x4*)(As + m * ASTR + k) = v;
    }
    __syncthreads();
    const int n0 = wave * (J * 16);
    floatx4 acc[4][J] = {};
#pragma unroll
    for (int ki = 0; ki < 8; ki++) {
        bf16x8 af[4], bfr[J];
#pragma unroll
        for (int i = 0; i < 4; i++)
            af[i] = *(const bf16x8*)(As + (i * 16 + l16) * ASTR + ki * 32 + quad * 8);
#pragma unroll
        for (int j = 0; j < J; j++)
            bfr[j] = *(const bf16x8*)(BT + (size_t)(n0 + j * 16 + l16) * 256 + ki * 32 + quad * 8);
#pragma unroll
        for (int i = 0; i < 4; i++)
#pragma unroll
            for (int j = 0; j < J; j++)
                acc[i][j] = MFMA16(af[i], bfr[j], acc[i][j]);
    }
    float* pat = patch[wave];
    const int prow = lane >> 2, pc = lane & 3;
#pragma unroll
    for (int i = 0; i < 4; i++)
#pragma unroll
        for (int j = 0; j < J; j++) {
            float bv = bias[n0 + j * 16 + l16];
#pragma unroll
            for (int r = 0; r < 4; r++)
                pat[(quad * 4 + r) * 20 + l16] = acc[i][j][r] + bv;
            float4 v4 = *(float4*)&pat[prow * 20 + pc * 4];   // same-wave RAW
            size_t gi = (size_t)(row0 + i * 16 + prow) * N + n0 + j * 16 + pc * 4;
            if (BF16OUT) {
                bf16x4 ob = {(__bf16)v4.x, (__bf16)v4.y, (__bf16)v4.z, (__bf16)v4.w};
                *(bf16x4*)(Cb + gi) = ob;
            } else {
                *(float4*)(Cf + gi) = v4;
            }
        }
}

// ---------------- MSDeformAttn sampling (unchanged from R4) ----------------
__global__ __launch_bounds__(256) void sample_k(const float* __restrict__ offa,
                                                const __bf16* __restrict__ valb,
                                                const float* __restrict__ refp,
                                                __bf16* __restrict__ outb) {
    const int r   = blockIdx.x;
    const int tid = threadIdx.x;
    if (r >= M_ROWS) {
        outb[(size_t)r * 256 + tid] = (__bf16)0.f;
        return;
    }
    __shared__ float2 s_wo[4][128];
    const int n = (r >= S_TOTAL) ? 1 : 0;

    if (tid < 128) {
        const int HLc[4] = {100, 50, 25, 13};
        const int STc[4] = {0, 10000, 12500, 13125};
        int lp = tid & 15, l = lp >> 2;
        float logit = offa[(size_t)r * 384 + 256 + tid];
        float mx = logit;
        mx = fmaxf(mx, __shfl_xor(mx, 1));
        mx = fmaxf(mx, __shfl_xor(mx, 2));
        mx = fmaxf(mx, __shfl_xor(mx, 4));
        mx = fmaxf(mx, __shfl_xor(mx, 8));
        float e = __expf(logit - mx);
        float s = e;
        s += __shfl_xor(s, 1); s += __shfl_xor(s, 2);
        s += __shfl_xor(s, 4); s += __shfl_xor(s, 8);
        float aw = e / s;

        float2 o2 = *(const float2*)(offa + (size_t)r * 384 + tid * 2);
        float rx = refp[((size_t)r * 4 + l) * 2];
        float ry = refp[((size_t)r * 4 + l) * 2 + 1];
        int   Wl = HLc[l];
        float x = rx * (float)Wl + o2.x - 0.5f;
        float y = ry * (float)Wl + o2.y - 0.5f;
        float xf = floorf(x), yf = floorf(y);
        float wx1 = x - xf, wy1 = y - yf;
        float wx0 = 1.f - wx1, wy0 = 1.f - wy1;
        int x0 = (int)xf, y0 = (int)yf;
        int base = n * S_TOTAL + STc[l];
#pragma unroll
        for (int c = 0; c < 4; c++) {
            int yy = y0 + (c >> 1), xx = x0 + (c & 1);
            bool valid = (yy >= 0) & (yy < Wl) & (xx >= 0) & (xx < Wl);
            int yc = min(max(yy, 0), Wl - 1);
            int xc = min(max(xx, 0), Wl - 1);
            float w = ((c >> 1) ? wy1 : wy0) * ((c & 1) ? wx1 : wx0);
            int off = (base + yc * Wl + xc) * 512;
            s_wo[c][tid] = make_float2(valid ? w * aw : 0.f, __int_as_float(off));
        }
    }
    __syncthreads();

    const int h  = tid >> 5;
    const int pg = (tid >> 2) & 7;
    const int cg = tid & 3;
    const char* vbase = (const char*)valb + h * 64 + cg * 16;
    float a[8] = {};
#pragma unroll
    for (int pp = 0; pp < 2; pp++) {
        int idx = h * 16 + pg * 2 + pp;
#pragma unroll
        for (int c = 0; c < 4; c++) {
            float2 wo = s_wo[c][idx];
            float  w  = wo.x;
            bf16x8 v  = *(const bf16x8*)(vbase + __float_as_int(wo.y));
#pragma unroll
            for (int k = 0; k < 8; k++) a[k] += w * (float)v[k];
        }
    }
#pragma unroll
    for (int k = 0; k < 8; k++) {
        a[k] += __shfl_xor(a[k], 4);
        a[k] += __shfl_xor(a[k], 8);
        a[k] += __shfl_xor(a[k], 16);
    }
    if (pg == 0) {
        bf16x8 res;
#pragma unroll
        for (int k = 0; k < 8; k++) res[k] = (__bf16)a[k];
        *(bf16x8*)(outb + (size_t)r * 256 + h * 32 + cg * 8) = res;
    }
}

// ---------------- fused out-proj + residual + LN1 --------------------------
// x,xb = LN(src + outb@W_out + b_out). BM=64, N=256 (full rows in block).
__global__ __launch_bounds__(512, 4) void oln_k(
    const __bf16* __restrict__ A, const __bf16* __restrict__ BT,
    const float* __restrict__ bias, const float* __restrict__ src,
    const float* __restrict__ g, const float* __restrict__ be,
    float* __restrict__ x, __bf16* __restrict__ xb) {
    constexpr int ASTR = 264;
    __shared__ __align__(16) __bf16 As[64 * ASTR];
    __shared__ __align__(16) float patch[8][16 * 20];
    __shared__ float2 rowred[64][9];
    const int tid = threadIdx.x, wave = tid >> 6, lane = tid & 63;
    const int l16 = lane & 15, quad = lane >> 4;
    const int prow = lane >> 2, pc = lane & 3;
    const int row0 = blockIdx.x * 64;
#pragma unroll
    for (int p = 0; p < 4; p++) {
        int fg = p * 512 + tid;
        int m = fg >> 5, gg = fg & 31;
        bf16x8 v = *(const bf16x8*)(A + (size_t)(row0 + m) * 256 + gg * 8);
        *(bf16x8*)(As + m * ASTR + gg * 8) = v;
    }
    __syncthreads();
    const int n0 = wave * 32;
    floatx4 acc[4][2] = {};
#pragma unroll
    for (int ki = 0; ki < 8; ki++) {
        bf16x8 af[4], bfr[2];
#pragma unroll
        for (int i = 0; i < 4; i++)
            af[i] = *(const bf16x8*)(As + (i * 16 + l16) * ASTR + ki * 32 + quad * 8);
#pragma unroll
        for (int j = 0; j < 2; j++)
            bfr[j] = *(const bf16x8*)(BT + (size_t)(n0 + j * 16 + l16) * 256 + ki * 32 + quad * 8);
#pragma unroll
        for (int i = 0; i < 4; i++)
#pragma unroll
            for (int j = 0; j < 2; j++)
                acc[i][j] = MFMA16(af[i], bfr[j], acc[i][j]);
    }
    // epilogue: transpose, +bias +src residual, rowwise LN across 8 waves
    float* pat = patch[wave];
    floatx4 v4[4][2];
#pragma unroll
    for (int i = 0; i < 4; i++) {
        int rowc = min(row0 + i * 16 + prow, M_ROWS - 1);
        float s_par = 0.f, q_par = 0.f;
#pragma unroll
        for (int j = 0; j < 2; j++) {
            float bv = bias[n0 + j * 16 + l16];
#pragma unroll
            for (int r = 0; r < 4; r++)
                pat[(quad * 4 + r) * 20 + l16] = acc[i][j][r] + bv;
            float4 t4 = *(float4*)&pat[prow * 20 + pc * 4];
            float4 r4 = *(const float4*)(src + (size_t)rowc * 256 + n0 + j * 16 + pc * 4);
            floatx4 w; w[0] = t4.x + r4.x; w[1] = t4.y + r4.y;
            w[2] = t4.z + r4.z; w[3] = t4.w + r4.w;
            v4[i][j] = w;
            s_par += w[0] + w[1] + w[2] + w[3];
            q_par += w[0] * w[0] + w[1] * w[1] + w[2] * w[2] + w[3] * w[3];
        }
        s_par += __shfl_xor(s_par, 1); s_par += __shfl_xor(s_par, 2);
        q_par += __shfl_xor(q_par, 1); q_par += __shfl_xor(q_par, 2);
        if (pc == 0) rowred[i * 16 + prow][wave] = make_float2(s_par, q_par);
    }
    __syncthreads();
#pragma unroll
    for (int i = 0; i < 4; i++) {
        float ss = 0.f, qq = 0.f;
#pragma unroll
        for (int w8 = 0; w8 < 8; w8++) {
            float2 t = rowred[i * 16 + prow][w8];
            ss += t.x; qq += t.y;
        }
        float mean = ss * (1.f / 256.f);
        float var  = qq * (1.f / 256.f) - mean * mean;
        float rstd = rsqrtf(var + 1e-5f);
#pragma unroll
        for (int j = 0; j < 2; j++) {
            int col = n0 + j * 16 + pc * 4;
            float4 g4 = *(const float4*)(g + col);
            float4 b4 = *(const float4*)(be + col);
            floatx4 w = v4[i][j];
            float4 o4;
            o4.x = (w[0] - mean) * rstd * g4.x + b4.x;
            o4.y = (w[1] - mean) * rstd * g4.y + b4.y;
            o4.z = (w[2] - mean) * rstd * g4.z + b4.z;
            o4.w = (w[3] - mean) * rstd * g4.w + b4.w;
            size_t gi = (size_t)(row0 + i * 16 + prow) * 256 + col;
            *(float4*)(x + gi) = o4;
            bf16x4 ob = {(__bf16)o4.x, (__bf16)o4.y, (__bf16)o4.z, (__bf16)o4.w};
            *(bf16x4*)(xb + gi) = ob;
        }
    }
}

// ---------------- fused FFN + residual + LN2 -------------------------------
// out = LN(x + relu(xb@W1+b1)@W2 + b2). BM=32; h kept in LDS (two 512 halves).
__global__ __launch_bounds__(512, 4) void ffn_k(
    const __bf16* __restrict__ xb, const __bf16* __restrict__ W1T,
    const __bf16* __restrict__ W2T, const float* __restrict__ b1,
    const float* __restrict__ b2, const float* __restrict__ x,
    const float* __restrict__ g, const float* __restrict__ be,
    float* __restrict__ out) {
    constexpr int ASTR = 264, HSTR = 520;
    __shared__ __align__(16) __bf16 As[32 * ASTR];    // 16.5 KB
    __shared__ __align__(16) __bf16 Hs[32 * HSTR];    // 32.5 KB
    __shared__ __align__(16) float patch[8][16 * 20]; // 10 KB
    __shared__ float2 rowred[32][9];
    const int tid = threadIdx.x, wave = tid >> 6, lane = tid & 63;
    const int l16 = lane & 15, quad = lane >> 4;
    const int prow = lane >> 2, pc = lane & 3;
    const int row0 = blockIdx.x * 32;
    float* pat = patch[wave];
#pragma unroll
    for (int p = 0; p < 2; p++) {
        int fg = p * 512 + tid;
        int m = fg >> 5, gg = fg & 31;
        bf16x8 v = *(const bf16x8*)(xb + (size_t)(row0 + m) * 256 + gg * 8);
        *(bf16x8*)(As + m * ASTR + gg * 8) = v;
    }
    __syncthreads();
    floatx4 facc[2][2] = {};
    for (int hc = 0; hc < 2; hc++) {
        // ---- h-half = relu(A @ W1[:, hc*512 .. +512) + b1) ----------------
        floatx4 hacc[2][4] = {};
#pragma unroll
        for (int ki = 0; ki < 8; ki++) {
            bf16x8 af[2], bfr[4];
#pragma unroll
            for (int i = 0; i < 2; i++)
                af[i] = *(const bf16x8*)(As + (i * 16 + l16) * ASTR + ki * 32 + quad * 8);
#pragma unroll
            for (int j = 0; j < 4; j++) {
                int nn = hc * 512 + wave * 64 + j * 16 + l16;
                bfr[j] = *(const bf16x8*)(W1T + (size_t)nn * 256 + ki * 32 + quad * 8);
            }
#pragma unroll
            for (int i = 0; i < 2; i++)
#pragma unroll
                for (int j = 0; j < 4; j++)
                    hacc[i][j] = MFMA16(af[i], bfr[j], hacc[i][j]);
        }
        // write h-half to LDS (bias+relu, transposed to row-major bf16)
#pragma unroll
        for (int i = 0; i < 2; i++)
#pragma unroll
            for (int j = 0; j < 4; j++) {
                float bv = b1[hc * 512 + wave * 64 + j * 16 + l16];
#pragma unroll
                for (int r = 0; r < 4; r++)
                    pat[(quad * 4 + r) * 20 + l16] = fmaxf(hacc[i][j][r] + bv, 0.f);
                float4 t4 = *(float4*)&pat[prow * 20 + pc * 4];
                bf16x4 h4 = {(__bf16)t4.x, (__bf16)t4.y, (__bf16)t4.z, (__bf16)t4.w};
                *(bf16x4*)(Hs + (i * 16 + prow) * HSTR + wave * 64 + j * 16 + pc * 4) = h4;
            }
        __syncthreads();
        // ---- facc += h-half @ W2[hc*512 .. +512, :] ------------------------
#pragma unroll
        for (int ki = 0; ki < 16; ki++) {
            bf16x8 ah[2], bfr[2];
#pragma unroll
            for (int i = 0; i < 2; i++)
                ah[i] = *(const bf16x8*)(Hs + (i * 16 + l16) * HSTR + ki * 32 + quad * 8);
#pragma unroll
            for (int j = 0; j < 2; j++) {
                int nn = wave * 32 + j * 16 + l16;
                bfr[j] = *(const bf16x8*)(W2T + (size_t)nn * 1024 + hc * 512 + ki * 32 + quad * 8);
            }
#pragma unroll
            for (int i = 0; i < 2; i++)
#pragma unroll
                for (int j = 0; j < 2; j++)
                    facc[i][j] = MFMA16(ah[i], bfr[j], facc[i][j]);
        }
        __syncthreads();        // Hs reusable for next half
    }
    // ---- epilogue: +b2, +x residual, LN2, store out (valid rows only) -----
    const int n0 = wave * 32;
    floatx4 v4[2][2];
#pragma unroll
    for (int i = 0; i < 2; i++) {
        int rowi = row0 + i * 16 + prow;
        float s_par = 0.f, q_par = 0.f;
#pragma unroll
        for (int j = 0; j < 2; j++) {
            float bv = b2[n0 + j * 16 + l16];
#pragma unroll
            for (int r = 0; r < 4; r++)
                pat[(quad * 4 + r) * 20 + l16] = facc[i][j][r] + bv;
            float4 t4 = *(float4*)&pat[prow * 20 + pc * 4];
            float4 r4 = *(const float4*)(x + (size_t)rowi * 256 + n0 + j * 16 + pc * 4);
            floatx4 w; w[0] = t4.x + r4.x; w[1] = t4.y + r4.y;
            w[2] = t4.z + r4.z; w[3] = t4.w + r4.w;
            v4[i][j] = w;
            s_par += w[0] + w[1] + w[2] + w[3];
            q_par += w[0] * w[0] + w[1] * w[1] + w[2] * w[2] + w[3] * w[3];
        }
        s_par += __shfl_xor(s_par, 1); s_par += __shfl_xor(s_par, 2);
        q_par += __shfl_xor(q_par, 1); q_par += __shfl_xor(q_par, 2);
        if (pc == 0) rowred[i * 16 + prow][wave] = make_float2(s_par, q_par);
    }
    __syncthreads();
#pragma unroll
    for (int i = 0; i < 2; i++) {
        float ss = 0.f, qq = 0.f;
#pragma unroll
        for (int w8 = 0; w8 < 8; w8++) {
            float2 t = rowred[i * 16 + prow][w8];
            ss += t.x; qq += t.y;
        }
        float mean = ss * (1.f / 256.f);
        float var  = qq * (1.f / 256.f) - mean * mean;
        float rstd = rsqrtf(var + 1e-5f);
        int row = row0 + i * 16 + prow;
        if (row < M_ROWS) {
#pragma unroll
            for (int j = 0; j < 2; j++) {
                int col = n0 + j * 16 + pc * 4;
                float4 g4 = *(const float4*)(g + col);
                float4 b4 = *(const float4*)(be + col);
                floatx4 w = v4[i][j];
                float4 o4;
                o4.x = (w[0] - mean) * rstd * g4.x + b4.x;
                o4.y = (w[1] - mean) * rstd * g4.y + b4.y;
                o4.z = (w[2] - mean) * rstd * g4.z + b4.z;
                o4.w = (w[3] - mean) * rstd * g4.w + b4.w;
                *(float4*)(out + (size_t)row * 256 + col) = o4;
            }
        }
    }
}

// ---------------------------------------------------------------------------
extern "C" void kernel_launch(void* const* d_in, const int* in_sizes, int n_in,
                              void* d_out, int out_size, void* d_ws, size_t ws_size,
                              hipStream_t stream) {
    const float* src  = (const float*)d_in[0];
    const float* pos  = (const float*)d_in[1];
    const float* refp = (const float*)d_in[2];
    const float* W_off  = (const float*)d_in[5];
    const float* b_off  = (const float*)d_in[6];
    const float* W_attn = (const float*)d_in[7];
    const float* b_attn = (const float*)d_in[8];
    const float* W_val  = (const float*)d_in[9];
    const float* b_val  = (const float*)d_in[10];
    const float* W_out  = (const float*)d_in[11];
    const float* b_out  = (const float*)d_in[12];
    const float* W1     = (const float*)d_in[13];
    const float* b1     = (const float*)d_in[14];
    const float* W2     = (const float*)d_in[15];
    const float* b2     = (const float*)d_in[16];
    const float* g1     = (const float*)d_in[17];
    const float* beta1  = (const float*)d_in[18];
    const float* g2     = (const float*)d_in[19];
    const float* beta2  = (const float*)d_in[20];
    float* out = (float*)d_out;

    // ---- workspace layout (peak ~70 MB) -----------------------------------
    const size_t RB = (size_t)M_PAD * 256 * 2;   // 13.6 MB (bf16 row256)
    const size_t RF = (size_t)M_PAD * 256 * 4;   // 27.3 MB (f32  row256)
    char* ws = (char*)d_ws;
    __bf16* outb = (__bf16*)(ws);                     //  0 .. 13.6
    __bf16* valb = (__bf16*)(ws + RB);                // 13.6 .. 27.3
    float*  offa = (float*)(ws + 2 * RB);             // 27.3 .. 68.2 (M_PAD x 384)
    float*  x    = (float*)(ws + 2 * RB);             // reuse: offa dead post-sample
    __bf16* xb   = (__bf16*)(ws + 2 * RB + RF);       // 54.6 .. 68.2
    char*   regW = ws + 2 * RB + (size_t)M_PAD * 384 * 4;   // 68.2 MB

    __bf16* WTcomb = (__bf16*)regW;
    __bf16* WTval  = (__bf16*)(regW + 196608);
    __bf16* WTout  = (__bf16*)(regW + 327680);
    __bf16* WT1    = (__bf16*)(regW + 458752);
    __bf16* WT2    = (__bf16*)(regW + 983040);
    float*  bc     = (float*)(regW + 1507328);

    cvt_k<<<185, 256, 0, stream>>>(W_off, W_attn, W_val, W_out, W1, W2,
                                   b_off, b_attn, WTcomb, bc);

    gemm_src<3, true, false><<<416, 512, 0, stream>>>(
        src, pos, WTcomb, bc, offa, nullptr, 384);
    gemm_src<2, false, true><<<416, 512, 0, stream>>>(
        src, src, WTval, b_val, nullptr, valb, 256);

    sample_k<<<M_PAD, 256, 0, stream>>>(offa, valb, refp, outb);

    oln_k<<<416, 512, 0, stream>>>(outb, WTout, b_out, src, g1, beta1, x, xb);

    ffn_k<<<832, 512, 0, stream>>>(xb, WT1, WT2, b1, b2, x, g2, beta2, out);
}